// Round 1
// baseline (643.981 us; speedup 1.0000x reference)
//
#include <hip/hip_runtime.h>
#include <hip/hip_bf16.h>
#include <math.h>

#define HW   4096
#define CCH  256
#define NE   8
#define HID  512
#define NTOK 65536

typedef short s16x8 __attribute__((ext_vector_type(8)));
typedef float f32x4 __attribute__((ext_vector_type(4)));

// ---------------- K transpose+cast: in (E,R,CC) fp32 -> out (E,CC,R) bf16 ----
__global__ __launch_bounds__(256) void k_transpose_cast(
    const float* __restrict__ in, __hip_bfloat16* __restrict__ out, int R, int CC)
{
    __shared__ float t[64][65];
    int tilesC = CC >> 6;
    int per = (R >> 6) * tilesC;
    int e = blockIdx.x / per, tt = blockIdx.x % per;
    int r0 = (tt / tilesC) << 6, c0 = (tt % tilesC) << 6;
    const float* ip = in + (size_t)e * R * CC;
    __hip_bfloat16* op = out + (size_t)e * R * CC;
    int lane = threadIdx.x & 63, g = threadIdx.x >> 6;
    for (int i = 0; i < 16; i++) {
        int r = i * 4 + g;
        t[r][lane] = ip[(size_t)(r0 + r) * CC + c0 + lane];
    }
    __syncthreads();
    for (int i = 0; i < 16; i++) {
        int r = i * 4 + g;  // output row within tile = input col
        op[(size_t)(c0 + r) * R + r0 + lane] = __float2bfloat16(t[lane][r]);
    }
}

// ---------------- K0: x transpose -> tokens bf16, fp32 router, top2 ---------
__global__ __launch_bounds__(256) void k_router(
    const float* __restrict__ x, const float* __restrict__ Wr, const float* __restrict__ br,
    __hip_bfloat16* __restrict__ tokens, int* __restrict__ pair, float2* __restrict__ wts,
    int* __restrict__ meta /* counts at [0..8) */)
{
    __shared__ float xt[CCH][65];
    __shared__ float wr[CCH][NE];
    __shared__ float lg[64][NE];
    __shared__ int lc[NE];
    int tid = threadIdx.x;
    int n0 = blockIdx.x * 64;
    int b = n0 >> 12, p0 = n0 & 4095;
    const float* xb = x + (size_t)b * CCH * HW + p0;
    for (int i = tid; i < CCH * NE; i += 256) ((float*)wr)[i] = Wr[i];
    if (tid < NE) lc[tid] = 0;
    int lane = tid & 63, wv = tid >> 6;
    for (int i = 0; i < 64; i++) {
        int c = i * 4 + wv;
        xt[c][lane] = xb[(size_t)c * HW + lane];
    }
    __syncthreads();
    // wave wv -> experts 2wv, 2wv+1 ; lane = local token
    float a0 = br[2 * wv], a1 = br[2 * wv + 1];
    for (int c = 0; c < CCH; c++) {
        float xv = xt[c][lane];
        a0 = fmaf(xv, wr[c][2 * wv], a0);
        a1 = fmaf(xv, wr[c][2 * wv + 1], a1);
    }
    lg[lane][2 * wv] = a0;
    lg[lane][2 * wv + 1] = a1;
    __syncthreads();
    if (wv == 0) {
        float v0 = -1e30f, v1 = -1e30f; int i0 = 0, i1 = 0;
        for (int e = 0; e < NE; e++) {
            float l = lg[lane][e];
            if (l > v0)      { v1 = v0; i1 = i0; v0 = l; i0 = e; }
            else if (l > v1) { v1 = l; i1 = e; }
        }
        float e1 = expf(v1 - v0);
        float s = 1.0f + e1;
        wts[n0 + lane] = make_float2(1.0f / s, e1 / s);
        pair[n0 + lane] = i0 | (i1 << 8);
        atomicAdd(&lc[i0], 1);
        atomicAdd(&lc[i1], 1);
    }
    __syncthreads();
    if (tid < NE && lc[tid] > 0) atomicAdd(&meta[tid], lc[tid]);
    for (int r = 0; r < 64; r++)
        tokens[(size_t)(n0 + r) * CCH + tid] = __float2bfloat16(xt[tid][r]);
}

// ---------------- K1: scan counts -> offsets/tilestarts ---------------------
// meta: [0..8) counts, [8..16) cursors, [16..25) offsets, [25..34) tilestart, [34] total
__global__ void k_scan(int* meta)
{
    if (threadIdx.x == 0) {
        int off = 0, toff = 0;
        for (int e = 0; e < NE; e++) {
            meta[16 + e] = off;
            meta[25 + e] = toff;
            int c = meta[e];
            off += c;
            toff += (c + 63) >> 6;
        }
        meta[24] = off;
        meta[33] = toff;
        meta[34] = toff;
    }
}

// ---------------- K2: scatter tokens into per-expert lists ------------------
__global__ __launch_bounds__(256) void k_scatter(
    const int* __restrict__ pair, const float2* __restrict__ wts,
    int* __restrict__ meta, int* __restrict__ assign_tok, float* __restrict__ assign_w,
    int2* __restrict__ tok_slots)
{
    __shared__ int lcount[NE];
    __shared__ int lbase[NE];
    int tid = threadIdx.x;
    int n = blockIdx.x * 256 + tid;
    if (tid < NE) lcount[tid] = 0;
    __syncthreads();
    int pr = pair[n];
    int e0 = pr & 0xff, e1 = (pr >> 8) & 0xff;
    int p0 = atomicAdd(&lcount[e0], 1);
    int p1 = atomicAdd(&lcount[e1], 1);
    __syncthreads();
    if (tid < NE) lbase[tid] = atomicAdd(&meta[8 + tid], lcount[tid]);
    __syncthreads();
    float2 w = wts[n];
    int s0 = meta[16 + e0] + lbase[e0] + p0;
    int s1 = meta[16 + e1] + lbase[e1] + p1;
    assign_tok[s0] = n; assign_w[s0] = w.x;
    assign_tok[s1] = n; assign_w[s1] = w.y;
    tok_slots[n] = make_int2(s0, s1);
}

// ---------------- K3: grouped fused MLP (the hot kernel) --------------------
// tile = 64 tokens of one expert; hidden processed in chunks of 64 via LDS.
__global__ __launch_bounds__(256) void k_expert(
    const __hip_bfloat16* __restrict__ tokens,
    const __hip_bfloat16* __restrict__ w1t,   // (E, HID, C)  = W1^T per expert
    const __hip_bfloat16* __restrict__ w2t,   // (E, C, HID)  = W2^T per expert
    const float* __restrict__ b1, const float* __restrict__ b2,
    const int* __restrict__ meta,
    const int* __restrict__ assign_tok, const float* __restrict__ assign_w,
    __hip_bfloat16* __restrict__ ybuf)
{
    __shared__ __align__(16) __hip_bfloat16 At[64 * 264];  // 64 x 256, pad +8
    __shared__ __align__(16) __hip_bfloat16 Ht[64 * 72];   // 64 x 64, pad +8
    __shared__ float wrow[64];
    __shared__ int trow[64];

    int total = meta[34];
    int bid = blockIdx.x;
    if (bid >= total) return;
    int e = 0;
    while (bid >= meta[25 + e + 1]) e++;
    int tile = bid - meta[25 + e];
    int cnt = meta[e];
    int r0 = tile << 6;
    int abase = meta[16 + e] + r0;
    int nrows = cnt - r0; if (nrows > 64) nrows = 64;

    int tid = threadIdx.x;
    if (tid < 64) {
        if (tid < nrows) { trow[tid] = assign_tok[abase + tid]; wrow[tid] = assign_w[abase + tid]; }
        else             { trow[tid] = 0; wrow[tid] = 0.0f; }
    }
    __syncthreads();

    // gather A tile (64 token rows, 256 ch) as 16B vectors
    {
        uint4* dst = (uint4*)At;
        for (int v = tid; v < 64 * 32; v += 256) {
            int row = v >> 5, col = v & 31;
            dst[row * 33 + col] = ((const uint4*)(tokens + (size_t)trow[row] * CCH))[col];
        }
    }
    __syncthreads();

    int lane = tid & 63, wv = tid >> 6;
    int quad = lane >> 4, l15 = lane & 15;
    f32x4 oacc[4][4];
#pragma unroll
    for (int i = 0; i < 4; i++)
#pragma unroll
        for (int j = 0; j < 4; j++) oacc[i][j] = (f32x4){0.f, 0.f, 0.f, 0.f};

    const __hip_bfloat16* w1e = w1t + (size_t)e * HID * CCH;
    const __hip_bfloat16* w2e = w2t + (size_t)e * CCH * HID;
    const float* b1e = b1 + e * HID;
    int m0 = wv << 4;       // GEMM1: this wave's 16 hidden-rows
    int n0c = wv << 6;      // GEMM2: this wave's 64 out-cols

    for (int hc = 0; hc < HID; hc += 64) {
        // ---- GEMM1: H[m0..m0+16][hc..hc+64] = A(64x256) @ W1 chunk
        f32x4 hacc[4];
#pragma unroll
        for (int i = 0; i < 4; i++) hacc[i] = (f32x4){0.f, 0.f, 0.f, 0.f};
#pragma unroll
        for (int kk = 0; kk < CCH; kk += 32) {
            s16x8 a = *(const s16x8*)(At + (m0 + l15) * 264 + kk + quad * 8);
#pragma unroll
            for (int nt = 0; nt < 4; nt++) {
                s16x8 bf = *(const s16x8*)(w1e + (size_t)(hc + nt * 16 + l15) * CCH + kk + quad * 8);
                hacc[nt] = __builtin_amdgcn_mfma_f32_16x16x32_bf16(a, bf, hacc[nt], 0, 0, 0);
            }
        }
        __syncthreads();   // previous chunk's GEMM2 done reading Ht
        // ---- bias + exact GELU -> Ht (bf16)
#pragma unroll
        for (int nt = 0; nt < 4; nt++) {
            float bias = b1e[hc + nt * 16 + l15];
#pragma unroll
            for (int r = 0; r < 4; r++) {
                float v = hacc[nt][r] + bias;
                float g = 0.5f * v * (1.0f + erff(v * 0.70710678118654752f));
                Ht[(m0 + quad * 4 + r) * 72 + nt * 16 + l15] = __float2bfloat16(g);
            }
        }
        __syncthreads();
        // ---- GEMM2: out[0..64][n0c..n0c+64] += Ht(64x64) @ W2 chunk
#pragma unroll
        for (int kk = 0; kk < 64; kk += 32) {
            s16x8 afr[4];
#pragma unroll
            for (int mt = 0; mt < 4; mt++)
                afr[mt] = *(const s16x8*)(Ht + (mt * 16 + l15) * 72 + kk + quad * 8);
#pragma unroll
            for (int nt = 0; nt < 4; nt++) {
                s16x8 bf = *(const s16x8*)(w2e + (size_t)(n0c + nt * 16 + l15) * HID + hc + kk + quad * 8);
#pragma unroll
                for (int mt = 0; mt < 4; mt++)
                    oacc[mt][nt] = __builtin_amdgcn_mfma_f32_16x16x32_bf16(afr[mt], bf, oacc[mt][nt], 0, 0, 0);
            }
        }
    }

    // ---- epilogue: (acc + b2) * route_weight -> ybuf[slot][c] bf16
    const float* b2e = b2 + e * CCH;
#pragma unroll
    for (int nt = 0; nt < 4; nt++) {
        int cc = n0c + nt * 16 + l15;
        float bias = b2e[cc];
#pragma unroll
        for (int mt = 0; mt < 4; mt++) {
#pragma unroll
            for (int r = 0; r < 4; r++) {
                int row = mt * 16 + quad * 4 + r;
                if (row < nrows) {
                    float v = (oacc[mt][nt][r] + bias) * wrow[row];
                    ybuf[(size_t)(abase + row) * CCH + cc] = __float2bfloat16(v);
                }
            }
        }
    }
}

// ---------------- K4: combine two expert outputs, transpose back, residual --
__global__ __launch_bounds__(256) void k_combine(
    const float* __restrict__ x, const __hip_bfloat16* __restrict__ ybuf,
    const int2* __restrict__ tok_slots, const float* __restrict__ scale,
    float* __restrict__ out)
{
    __shared__ float moe[CCH][65];
    __shared__ int2 slots[64];
    int tid = threadIdx.x;
    int n0 = blockIdx.x * 64;
    if (tid < 64) slots[tid] = tok_slots[n0 + tid];
    __syncthreads();
    for (int r = 0; r < 64; r++) {
        int2 s = slots[r];
        float y = __bfloat162float(ybuf[(size_t)s.x * CCH + tid]) +
                  __bfloat162float(ybuf[(size_t)s.y * CCH + tid]);
        moe[tid][r] = y;
    }
    __syncthreads();
    float sc = scale[0];
    int b = n0 >> 12, p0 = n0 & 4095;
    const float* xb = x + (size_t)b * CCH * HW + p0;
    float* ob = out + (size_t)b * CCH * HW + p0;
    int lane = tid & 63, wv = tid >> 6;
    for (int i = 0; i < 64; i++) {
        int c = i * 4 + wv;
        ob[(size_t)c * HW + lane] = xb[(size_t)c * HW + lane] + sc * moe[c][lane];
    }
}

// ---------------- launch ----------------------------------------------------
extern "C" void kernel_launch(void* const* d_in, const int* in_sizes, int n_in,
                              void* d_out, int out_size, void* d_ws, size_t ws_size,
                              hipStream_t stream)
{
    const float* x     = (const float*)d_in[0];
    const float* Wr    = (const float*)d_in[1];
    const float* br    = (const float*)d_in[2];
    const float* W1    = (const float*)d_in[3];
    const float* b1    = (const float*)d_in[4];
    const float* W2    = (const float*)d_in[5];
    const float* b2    = (const float*)d_in[6];
    const float* scale = (const float*)d_in[7];
    float* out = (float*)d_out;

    char* ws = (char*)d_ws;
    __hip_bfloat16* tokens = (__hip_bfloat16*)(ws);                 // 33,554,432 B
    __hip_bfloat16* w1t    = (__hip_bfloat16*)(ws + 33554432);      //  2,097,152 B
    __hip_bfloat16* w2t    = (__hip_bfloat16*)(ws + 35651584);      //  2,097,152 B
    __hip_bfloat16* ybuf   = (__hip_bfloat16*)(ws + 37748736);      // 67,108,864 B
    int*    assign_tok = (int*)   (ws + 104857600);                 //    524,288 B
    float*  assign_w   = (float*) (ws + 105381888);                 //    524,288 B
    int2*   tok_slots  = (int2*)  (ws + 105906176);                 //    524,288 B
    int*    pair       = (int*)   (ws + 106430464);                 //    262,144 B
    float2* wts        = (float2*)(ws + 106692608);                 //    524,288 B
    int*    meta       = (int*)   (ws + 107216896);                 //        256 B

    hipMemsetAsync(meta, 0, 64, stream);  // counts + cursors
    k_transpose_cast<<<256, 256, 0, stream>>>(W1, w1t, 256, 512);
    k_transpose_cast<<<256, 256, 0, stream>>>(W2, w2t, 512, 256);
    k_router<<<1024, 256, 0, stream>>>(x, Wr, br, tokens, pair, wts, meta);
    k_scan<<<1, 64, 0, stream>>>(meta);
    k_scatter<<<256, 256, 0, stream>>>(pair, wts, meta, assign_tok, assign_w, tok_slots);
    k_expert<<<2056, 256, 0, stream>>>(tokens, w1t, w2t, b1, b2, meta,
                                       assign_tok, assign_w, ybuf);
    k_combine<<<1024, 256, 0, stream>>>(x, ybuf, tok_slots, scale, out);
}

// Round 2
// 464.862 us; speedup vs baseline: 1.3853x; 1.3853x over previous
//
#include <hip/hip_runtime.h>
#include <hip/hip_bf16.h>
#include <math.h>

#define HW   4096
#define CCH  256
#define NE   8
#define HID  512
#define NTOK 65536

typedef short s16x8 __attribute__((ext_vector_type(8)));
typedef float f32x4 __attribute__((ext_vector_type(4)));

// ---------------- K transpose+cast: in (E,R,CC) fp32 -> out (E,CC,R) bf16 ----
__global__ __launch_bounds__(256) void k_transpose_cast(
    const float* __restrict__ in, __hip_bfloat16* __restrict__ out, int R, int CC)
{
    __shared__ float t[64][65];
    int tilesC = CC >> 6;
    int per = (R >> 6) * tilesC;
    int e = blockIdx.x / per, tt = blockIdx.x % per;
    int r0 = (tt / tilesC) << 6, c0 = (tt % tilesC) << 6;
    const float* ip = in + (size_t)e * R * CC;
    __hip_bfloat16* op = out + (size_t)e * R * CC;
    int lane = threadIdx.x & 63, g = threadIdx.x >> 6;
    for (int i = 0; i < 16; i++) {
        int r = i * 4 + g;
        t[r][lane] = ip[(size_t)(r0 + r) * CC + c0 + lane];
    }
    __syncthreads();
    for (int i = 0; i < 16; i++) {
        int r = i * 4 + g;  // output row within tile = input col
        op[(size_t)(c0 + r) * R + r0 + lane] = __float2bfloat16(t[lane][r]);
    }
}

// ---------------- K0: x transpose -> tokens bf16, fp32 router, top2 ---------
__global__ __launch_bounds__(256) void k_router(
    const float* __restrict__ x, const float* __restrict__ Wr, const float* __restrict__ br,
    __hip_bfloat16* __restrict__ tokens, int* __restrict__ pair, float2* __restrict__ wts,
    int* __restrict__ meta /* counts at [0..8) */)
{
    __shared__ float xt[CCH][65];
    __shared__ float wr[CCH][NE];
    __shared__ float lg[64][NE];
    __shared__ int lc[NE];
    int tid = threadIdx.x;
    int n0 = blockIdx.x * 64;
    int b = n0 >> 12, p0 = n0 & 4095;
    const float* xb = x + (size_t)b * CCH * HW + p0;
    for (int i = tid; i < CCH * NE; i += 256) ((float*)wr)[i] = Wr[i];
    if (tid < NE) lc[tid] = 0;
    int lane = tid & 63, wv = tid >> 6;
    for (int i = 0; i < 64; i++) {
        int c = i * 4 + wv;
        xt[c][lane] = xb[(size_t)c * HW + lane];
    }
    __syncthreads();
    // wave wv -> experts 2wv, 2wv+1 ; lane = local token
    float a0 = br[2 * wv], a1 = br[2 * wv + 1];
    for (int c = 0; c < CCH; c++) {
        float xv = xt[c][lane];
        a0 = fmaf(xv, wr[c][2 * wv], a0);
        a1 = fmaf(xv, wr[c][2 * wv + 1], a1);
    }
    lg[lane][2 * wv] = a0;
    lg[lane][2 * wv + 1] = a1;
    __syncthreads();
    if (wv == 0) {
        float v0 = -1e30f, v1 = -1e30f; int i0 = 0, i1 = 0;
        for (int e = 0; e < NE; e++) {
            float l = lg[lane][e];
            if (l > v0)      { v1 = v0; i1 = i0; v0 = l; i0 = e; }
            else if (l > v1) { v1 = l; i1 = e; }
        }
        float e1 = expf(v1 - v0);
        float s = 1.0f + e1;
        wts[n0 + lane] = make_float2(1.0f / s, e1 / s);
        pair[n0 + lane] = i0 | (i1 << 8);
        atomicAdd(&lc[i0], 1);
        atomicAdd(&lc[i1], 1);
    }
    __syncthreads();
    if (tid < NE && lc[tid] > 0) atomicAdd(&meta[tid], lc[tid]);
    for (int r = 0; r < 64; r++)
        tokens[(size_t)(n0 + r) * CCH + tid] = __float2bfloat16(xt[tid][r]);
}

// ---------------- K1: scan counts -> offsets/tilestarts ---------------------
// meta: [0..8) counts, [8..16) cursors, [16..25) offsets, [25..34) tilestart, [34] total
__global__ void k_scan(int* meta)
{
    if (threadIdx.x == 0) {
        int off = 0, toff = 0;
        for (int e = 0; e < NE; e++) {
            meta[16 + e] = off;
            meta[25 + e] = toff;
            int c = meta[e];
            off += c;
            toff += (c + 63) >> 6;
        }
        meta[24] = off;
        meta[33] = toff;
        meta[34] = toff;
    }
}

// ---------------- K2: scatter tokens into per-expert lists ------------------
__global__ __launch_bounds__(256) void k_scatter(
    const int* __restrict__ pair, const float2* __restrict__ wts,
    int* __restrict__ meta, int* __restrict__ assign_tok, float* __restrict__ assign_w,
    int2* __restrict__ tok_slots)
{
    __shared__ int lcount[NE];
    __shared__ int lbase[NE];
    int tid = threadIdx.x;
    int n = blockIdx.x * 256 + tid;
    if (tid < NE) lcount[tid] = 0;
    __syncthreads();
    int pr = pair[n];
    int e0 = pr & 0xff, e1 = (pr >> 8) & 0xff;
    int p0 = atomicAdd(&lcount[e0], 1);
    int p1 = atomicAdd(&lcount[e1], 1);
    __syncthreads();
    if (tid < NE) lbase[tid] = atomicAdd(&meta[8 + tid], lcount[tid]);
    __syncthreads();
    float2 w = wts[n];
    int s0 = meta[16 + e0] + lbase[e0] + p0;
    int s1 = meta[16 + e1] + lbase[e1] + p1;
    assign_tok[s0] = n; assign_w[s0] = w.x;
    assign_tok[s1] = n; assign_w[s1] = w.y;
    tok_slots[n] = make_int2(s0, s1);
}

// ---------------- K3: grouped fused MLP (the hot kernel) --------------------
// 512 threads = 8 waves. Tile = 64 tokens of one expert.
// Wave wv: GEMM1 computes H[0:64][64wv:64wv+64] (full K=256, A gathered
// straight from global in MFMA A-frag layout, B = W1^T rows from global/L2).
// H round-trips LDS (C-layout -> A-layout). GEMM2: wave wv computes
// out[0:64][32wv:32wv+32] over K=512. Only 2 barriers per block.
__global__ __launch_bounds__(512) void k_expert(
    const __hip_bfloat16* __restrict__ tokens,
    const __hip_bfloat16* __restrict__ w1t,   // (E, HID, C)  = W1^T per expert
    const __hip_bfloat16* __restrict__ w2t,   // (E, C, HID)  = W2^T per expert
    const float* __restrict__ b1, const float* __restrict__ b2,
    const int* __restrict__ meta,
    const int* __restrict__ assign_tok, const float* __restrict__ assign_w,
    __hip_bfloat16* __restrict__ ybuf)
{
    __shared__ __align__(16) __hip_bfloat16 Hs[64 * 520];  // 64 x 512, pad +8
    __shared__ float wrow[64];
    __shared__ int trow[64];

    int total = meta[34];
    int bid = blockIdx.x;
    if (bid >= total) return;
    int e = 0;
    while (e < 7 && bid >= meta[25 + e + 1]) e++;
    int tile = bid - meta[25 + e];
    int cnt = meta[e];
    int r0 = tile << 6;
    int abase = meta[16 + e] + r0;
    int nrows = cnt - r0; if (nrows > 64) nrows = 64;

    int tid = threadIdx.x;
    if (tid < 64) {
        if (tid < nrows) { trow[tid] = assign_tok[abase + tid]; wrow[tid] = assign_w[abase + tid]; }
        else             { trow[tid] = 0; wrow[tid] = 0.0f; }
    }
    __syncthreads();

    int lane = tid & 63, wv = tid >> 6;      // wv in [0,8)
    int quad = lane >> 4, l15 = lane & 15;

    const __hip_bfloat16* w1e = w1t + (size_t)e * HID * CCH;
    const __hip_bfloat16* w2e = w2t + (size_t)e * CCH * HID;

    // ---- GEMM1: A-frags gathered directly from global (m=l15 token row,
    //      k contiguous), B-frags = W1^T rows (each wave owns distinct rows).
    const s16x8* ap[4];
#pragma unroll
    for (int mt = 0; mt < 4; mt++)
        ap[mt] = (const s16x8*)(tokens + (size_t)trow[mt * 16 + l15] * CCH + quad * 8);
    const s16x8* bp[4];
#pragma unroll
    for (int nt = 0; nt < 4; nt++)
        bp[nt] = (const s16x8*)(w1e + (size_t)(wv * 64 + nt * 16 + l15) * CCH + quad * 8);

    f32x4 hacc[4][4];
#pragma unroll
    for (int i = 0; i < 4; i++)
#pragma unroll
        for (int j = 0; j < 4; j++) hacc[i][j] = (f32x4){0.f, 0.f, 0.f, 0.f};

#pragma unroll
    for (int kk = 0; kk < 8; kk++) {         // K = 8 x 32
        s16x8 af[4], bfr[4];
#pragma unroll
        for (int mt = 0; mt < 4; mt++) af[mt] = ap[mt][kk * 4];
#pragma unroll
        for (int nt = 0; nt < 4; nt++) bfr[nt] = bp[nt][kk * 4];
#pragma unroll
        for (int mt = 0; mt < 4; mt++)
#pragma unroll
            for (int nt = 0; nt < 4; nt++)
                hacc[mt][nt] = __builtin_amdgcn_mfma_f32_16x16x32_bf16(af[mt], bfr[nt], hacc[mt][nt], 0, 0, 0);
    }

    // ---- bias + exact GELU -> Hs (bf16), C-layout scatter
    const float* b1e = b1 + e * HID;
#pragma unroll
    for (int nt = 0; nt < 4; nt++) {
        int col = wv * 64 + nt * 16 + l15;
        float bias = b1e[col];
#pragma unroll
        for (int mt = 0; mt < 4; mt++)
#pragma unroll
            for (int r = 0; r < 4; r++) {
                int row = mt * 16 + quad * 4 + r;
                float v = hacc[mt][nt][r] + bias;
                float g = 0.5f * v * (1.0f + erff(v * 0.70710678118654752f));
                Hs[row * 520 + col] = __float2bfloat16(g);
            }
    }
    __syncthreads();

    // ---- GEMM2: A = Hs rows (LDS), B = W2^T rows (global/L2)
    f32x4 oacc[4][2];
#pragma unroll
    for (int i = 0; i < 4; i++)
#pragma unroll
        for (int j = 0; j < 2; j++) oacc[i][j] = (f32x4){0.f, 0.f, 0.f, 0.f};

    const s16x8* hp[4];
#pragma unroll
    for (int mt = 0; mt < 4; mt++)
        hp[mt] = (const s16x8*)(Hs + (mt * 16 + l15) * 520 + quad * 8);
    const s16x8* b2p[2];
#pragma unroll
    for (int nt = 0; nt < 2; nt++)
        b2p[nt] = (const s16x8*)(w2e + (size_t)(wv * 32 + nt * 16 + l15) * HID + quad * 8);

#pragma unroll
    for (int kk = 0; kk < 16; kk++) {        // K = 16 x 32
        s16x8 hf[4], bfr[2];
#pragma unroll
        for (int mt = 0; mt < 4; mt++) hf[mt] = hp[mt][kk * 4];
#pragma unroll
        for (int nt = 0; nt < 2; nt++) bfr[nt] = b2p[nt][kk * 4];
#pragma unroll
        for (int mt = 0; mt < 4; mt++)
#pragma unroll
            for (int nt = 0; nt < 2; nt++)
                oacc[mt][nt] = __builtin_amdgcn_mfma_f32_16x16x32_bf16(hf[mt], bfr[nt], oacc[mt][nt], 0, 0, 0);
    }

    // ---- epilogue: (acc + b2) * route_weight -> ybuf[slot][c] bf16
    const float* b2e = b2 + e * CCH;
#pragma unroll
    for (int nt = 0; nt < 2; nt++) {
        int cc = wv * 32 + nt * 16 + l15;
        float bias = b2e[cc];
#pragma unroll
        for (int mt = 0; mt < 4; mt++) {
#pragma unroll
            for (int r = 0; r < 4; r++) {
                int row = mt * 16 + quad * 4 + r;
                if (row < nrows) {
                    float v = (oacc[mt][nt][r] + bias) * wrow[row];
                    ybuf[(size_t)(abase + row) * CCH + cc] = __float2bfloat16(v);
                }
            }
        }
    }
}

// ---------------- K4: combine two expert outputs, transpose back, residual --
__global__ __launch_bounds__(256) void k_combine(
    const float* __restrict__ x, const __hip_bfloat16* __restrict__ ybuf,
    const int2* __restrict__ tok_slots, const float* __restrict__ scale,
    float* __restrict__ out)
{
    __shared__ float moe[CCH][65];
    __shared__ int2 slots[64];
    int tid = threadIdx.x;
    int n0 = blockIdx.x * 64;
    if (tid < 64) slots[tid] = tok_slots[n0 + tid];
    __syncthreads();
    for (int r = 0; r < 64; r++) {
        int2 s = slots[r];
        float y = __bfloat162float(ybuf[(size_t)s.x * CCH + tid]) +
                  __bfloat162float(ybuf[(size_t)s.y * CCH + tid]);
        moe[tid][r] = y;
    }
    __syncthreads();
    float sc = scale[0];
    int b = n0 >> 12, p0 = n0 & 4095;
    const float* xb = x + (size_t)b * CCH * HW + p0;
    float* ob = out + (size_t)b * CCH * HW + p0;
    int lane = tid & 63, wv = tid >> 6;
    for (int i = 0; i < 64; i++) {
        int c = i * 4 + wv;
        ob[(size_t)c * HW + lane] = xb[(size_t)c * HW + lane] + sc * moe[c][lane];
    }
}

// ---------------- launch ----------------------------------------------------
extern "C" void kernel_launch(void* const* d_in, const int* in_sizes, int n_in,
                              void* d_out, int out_size, void* d_ws, size_t ws_size,
                              hipStream_t stream)
{
    const float* x     = (const float*)d_in[0];
    const float* Wr    = (const float*)d_in[1];
    const float* br    = (const float*)d_in[2];
    const float* W1    = (const float*)d_in[3];
    const float* b1    = (const float*)d_in[4];
    const float* W2    = (const float*)d_in[5];
    const float* b2    = (const float*)d_in[6];
    const float* scale = (const float*)d_in[7];
    float* out = (float*)d_out;

    char* ws = (char*)d_ws;
    __hip_bfloat16* tokens = (__hip_bfloat16*)(ws);                 // 33,554,432 B
    __hip_bfloat16* w1t    = (__hip_bfloat16*)(ws + 33554432);      //  2,097,152 B
    __hip_bfloat16* w2t    = (__hip_bfloat16*)(ws + 35651584);      //  2,097,152 B
    __hip_bfloat16* ybuf   = (__hip_bfloat16*)(ws + 37748736);      // 67,108,864 B
    int*    assign_tok = (int*)   (ws + 104857600);                 //    524,288 B
    float*  assign_w   = (float*) (ws + 105381888);                 //    524,288 B
    int2*   tok_slots  = (int2*)  (ws + 105906176);                 //    524,288 B
    int*    pair       = (int*)   (ws + 106430464);                 //    262,144 B
    float2* wts        = (float2*)(ws + 106692608);                 //    524,288 B
    int*    meta       = (int*)   (ws + 107216896);                 //        256 B

    hipMemsetAsync(meta, 0, 64, stream);  // counts + cursors
    k_transpose_cast<<<256, 256, 0, stream>>>(W1, w1t, 256, 512);
    k_transpose_cast<<<256, 256, 0, stream>>>(W2, w2t, 512, 256);
    k_router<<<1024, 256, 0, stream>>>(x, Wr, br, tokens, pair, wts, meta);
    k_scan<<<1, 64, 0, stream>>>(meta);
    k_scatter<<<256, 256, 0, stream>>>(pair, wts, meta, assign_tok, assign_w, tok_slots);
    k_expert<<<2056, 512, 0, stream>>>(tokens, w1t, w2t, b1, b2, meta,
                                       assign_tok, assign_w, ybuf);
    k_combine<<<1024, 256, 0, stream>>>(x, ybuf, tok_slots, scale, out);
}

// Round 3
// 368.229 us; speedup vs baseline: 1.7489x; 1.2624x over previous
//
#include <hip/hip_runtime.h>
#include <hip/hip_bf16.h>
#include <math.h>

#define HW   4096
#define CCH  256
#define NE   8
#define HID  512
#define NTOK 65536
#define PADH 260   // Hs row pitch (elems): +4 pad -> conflict-free writes, 4-way reads

typedef short s16x8 __attribute__((ext_vector_type(8)));
typedef float f32x4 __attribute__((ext_vector_type(4)));

// ---------------- K transpose+cast: in (E,R,CC) fp32 -> out (E,CC,R) bf16 ----
__global__ __launch_bounds__(256) void k_transpose_cast(
    const float* __restrict__ in, __hip_bfloat16* __restrict__ out, int R, int CC)
{
    __shared__ float t[64][65];
    int tilesC = CC >> 6;
    int per = (R >> 6) * tilesC;
    int e = blockIdx.x / per, tt = blockIdx.x % per;
    int r0 = (tt / tilesC) << 6, c0 = (tt % tilesC) << 6;
    const float* ip = in + (size_t)e * R * CC;
    __hip_bfloat16* op = out + (size_t)e * R * CC;
    int lane = threadIdx.x & 63, g = threadIdx.x >> 6;
    for (int i = 0; i < 16; i++) {
        int r = i * 4 + g;
        t[r][lane] = ip[(size_t)(r0 + r) * CC + c0 + lane];
    }
    __syncthreads();
    for (int i = 0; i < 16; i++) {
        int r = i * 4 + g;
        op[(size_t)(c0 + r) * R + r0 + lane] = __float2bfloat16(t[lane][r]);
    }
}

// ---------------- K0: x transpose -> tokens bf16, fp32 router, top2 ---------
__global__ __launch_bounds__(256) void k_router(
    const float* __restrict__ x, const float* __restrict__ Wr, const float* __restrict__ br,
    __hip_bfloat16* __restrict__ tokens, int* __restrict__ pair, float2* __restrict__ wts,
    int* __restrict__ meta /* counts at [0..8) */)
{
    __shared__ float xt[CCH][65];
    __shared__ float wr[CCH][NE];
    __shared__ float lg[64][NE];
    __shared__ int lc[NE];
    int tid = threadIdx.x;
    int n0 = blockIdx.x * 64;
    int b = n0 >> 12, p0 = n0 & 4095;
    const float* xb = x + (size_t)b * CCH * HW + p0;
    for (int i = tid; i < CCH * NE; i += 256) ((float*)wr)[i] = Wr[i];
    if (tid < NE) lc[tid] = 0;
    int lane = tid & 63, wv = tid >> 6;
    for (int i = 0; i < 64; i++) {
        int c = i * 4 + wv;
        xt[c][lane] = xb[(size_t)c * HW + lane];
    }
    __syncthreads();
    float a0 = br[2 * wv], a1 = br[2 * wv + 1];
    for (int c = 0; c < CCH; c++) {
        float xv = xt[c][lane];
        a0 = fmaf(xv, wr[c][2 * wv], a0);
        a1 = fmaf(xv, wr[c][2 * wv + 1], a1);
    }
    lg[lane][2 * wv] = a0;
    lg[lane][2 * wv + 1] = a1;
    __syncthreads();
    if (wv == 0) {
        float v0 = -1e30f, v1 = -1e30f; int i0 = 0, i1 = 0;
        for (int e = 0; e < NE; e++) {
            float l = lg[lane][e];
            if (l > v0)      { v1 = v0; i1 = i0; v0 = l; i0 = e; }
            else if (l > v1) { v1 = l; i1 = e; }
        }
        float e1 = expf(v1 - v0);
        float s = 1.0f + e1;
        wts[n0 + lane] = make_float2(1.0f / s, e1 / s);
        pair[n0 + lane] = i0 | (i1 << 8);
        atomicAdd(&lc[i0], 1);
        atomicAdd(&lc[i1], 1);
    }
    __syncthreads();
    if (tid < NE && lc[tid] > 0) atomicAdd(&meta[tid], lc[tid]);
    for (int r = 0; r < 64; r++)
        tokens[(size_t)(n0 + r) * CCH + tid] = __float2bfloat16(xt[tid][r]);
}

// ---------------- K1: scan counts -> offsets/tilestarts ---------------------
// meta: [0..8) counts, [8..16) cursors, [16..25) offsets, [25..34) tilestart, [34] total
__global__ void k_scan(int* meta)
{
    if (threadIdx.x == 0) {
        int off = 0, toff = 0;
        for (int e = 0; e < NE; e++) {
            meta[16 + e] = off;
            meta[25 + e] = toff;
            int c = meta[e];
            off += c;
            toff += (c + 63) >> 6;
        }
        meta[24] = off;
        meta[33] = toff;
        meta[34] = toff;
    }
}

// ---------------- K2: scatter tokens into per-expert lists ------------------
__global__ __launch_bounds__(256) void k_scatter(
    const int* __restrict__ pair, const float2* __restrict__ wts,
    int* __restrict__ meta, int* __restrict__ assign_tok, float* __restrict__ assign_w,
    int2* __restrict__ tok_slots)
{
    __shared__ int lcount[NE];
    __shared__ int lbase[NE];
    int tid = threadIdx.x;
    int n = blockIdx.x * 256 + tid;
    if (tid < NE) lcount[tid] = 0;
    __syncthreads();
    int pr = pair[n];
    int e0 = pr & 0xff, e1 = (pr >> 8) & 0xff;
    int p0 = atomicAdd(&lcount[e0], 1);
    int p1 = atomicAdd(&lcount[e1], 1);
    __syncthreads();
    if (tid < NE) lbase[tid] = atomicAdd(&meta[8 + tid], lcount[tid]);
    __syncthreads();
    float2 w = wts[n];
    int s0 = meta[16 + e0] + lbase[e0] + p0;
    int s1 = meta[16 + e1] + lbase[e1] + p1;
    assign_tok[s0] = n; assign_w[s0] = w.x;
    assign_tok[s1] = n; assign_w[s1] = w.y;
    tok_slots[n] = make_int2(s0, s1);
}

// ---------------- K3: grouped fused MLP (the hot kernel) --------------------
// 512 threads = 8 waves, 64-token tile. Hidden processed in 2 halves of 256:
//   GEMM1 half h: wave wv computes H[0:64][h*256+32wv : +32] (K=256, A from
//   LDS frag-linear tile, B = W1^T rows from global/L2).
//   GEMM2 half h: wave wv accumulates out[0:64][32wv : +32] over K=h-half.
// hacc 32 + oacc 32 AGPRs -> fits 128-reg budget -> 2 blocks/CU resident.
__global__ __launch_bounds__(512, 4) void k_expert(
    const __hip_bfloat16* __restrict__ tokens,
    const __hip_bfloat16* __restrict__ w1t,   // (E, HID, C)  = W1^T per expert
    const __hip_bfloat16* __restrict__ w2t,   // (E, C, HID)  = W2^T per expert
    const float* __restrict__ b1, const float* __restrict__ b2,
    const int* __restrict__ meta,
    const int* __restrict__ assign_tok, const float* __restrict__ assign_w,
    __hip_bfloat16* __restrict__ ybuf)
{
    // A tile, frag-linear: 16B unit U = mt*512 + (kk*4+quad)*16 + l15
    // (unit U holds token row (U>>9)*16+(U&15), k-chunk (U>>4)&31)
    __shared__ __align__(16) __hip_bfloat16 Af[64 * 256];      // 32 KB
    __shared__ __align__(16) __hip_bfloat16 Hs[64 * PADH];     // 33.3 KB
    __shared__ float wrow[64];
    __shared__ int trow[64];

    int total = meta[34];
    int bid = blockIdx.x;
    if (bid >= total) return;
    int e = 0;
    while (e < 7 && bid >= meta[25 + e + 1]) e++;
    int tile = bid - meta[25 + e];
    int cnt = meta[e];
    int r0 = tile << 6;
    int abase = meta[16 + e] + r0;
    int nrows = cnt - r0; if (nrows > 64) nrows = 64;

    int tid = threadIdx.x;
    if (tid < 64) {
        if (tid < nrows) { trow[tid] = assign_tok[abase + tid]; wrow[tid] = assign_w[abase + tid]; }
        else             { trow[tid] = 0; wrow[tid] = 0.0f; }
    }
    __syncthreads();

    // ---- stage A tile into LDS (frag-linear; lane-linear writes => no conflicts)
    {
        uint4* dst = (uint4*)Af;
#pragma unroll
        for (int j = 0; j < 4; j++) {
            int row = j * 16 + (tid & 15);
            int chunk = (tid >> 4) & 31;
            dst[j * 512 + tid] = ((const uint4*)(tokens + (size_t)trow[row] * CCH))[chunk];
        }
    }

    int lane = tid & 63, wv = tid >> 6;      // wv in [0,8)
    int quad = lane >> 4, l15 = lane & 15;

    const __hip_bfloat16* w1e = w1t + (size_t)e * HID * CCH;
    const __hip_bfloat16* w2e = w2t + (size_t)e * CCH * HID;
    const float* b1e = b1 + e * HID;

    const s16x8* apb = (const s16x8*)Af + quad * 16 + l15;   // + mt*512 + kk*64

    f32x4 oacc[4][2];
#pragma unroll
    for (int i = 0; i < 4; i++)
#pragma unroll
        for (int j = 0; j < 2; j++) oacc[i][j] = (f32x4){0.f, 0.f, 0.f, 0.f};

    __syncthreads();   // A tile visible

#pragma unroll
    for (int h = 0; h < 2; h++) {
        int c0 = h * 256 + wv * 32;          // absolute hidden col base for GEMM1
        // ---- GEMM1: hacc[mt][nt] over K=256
        const s16x8* bp0 = (const s16x8*)(w1e + (size_t)(c0)      * CCH + quad * 8);
        const s16x8* bp1 = (const s16x8*)(w1e + (size_t)(c0 + 16) * CCH + quad * 8);
        const s16x8* bq0 = (const s16x8*)((const __hip_bfloat16*)bp0 + (size_t)l15 * CCH);
        const s16x8* bq1 = (const s16x8*)((const __hip_bfloat16*)bp1 + (size_t)l15 * CCH);

        f32x4 hacc[4][2];
#pragma unroll
        for (int i = 0; i < 4; i++)
#pragma unroll
            for (int j = 0; j < 2; j++) hacc[i][j] = (f32x4){0.f, 0.f, 0.f, 0.f};

        s16x8 bf0 = bq0[0], bf1 = bq1[0];
#pragma unroll
        for (int kk = 0; kk < 8; kk++) {
            s16x8 bn0, bn1;
            if (kk < 7) { bn0 = bq0[(kk + 1) * 4]; bn1 = bq1[(kk + 1) * 4]; }
            s16x8 af[4];
#pragma unroll
            for (int mt = 0; mt < 4; mt++) af[mt] = apb[mt * 512 + kk * 4 * 16];
#pragma unroll
            for (int mt = 0; mt < 4; mt++) {
                hacc[mt][0] = __builtin_amdgcn_mfma_f32_16x16x32_bf16(af[mt], bf0, hacc[mt][0], 0, 0, 0);
                hacc[mt][1] = __builtin_amdgcn_mfma_f32_16x16x32_bf16(af[mt], bf1, hacc[mt][1], 0, 0, 0);
            }
            bf0 = bn0; bf1 = bn1;
        }

        __syncthreads();   // (h=1: GEMM2 of h=0 done reading Hs)
        // ---- bias + exact GELU -> Hs (local col cl in [0,256))
#pragma unroll
        for (int nt = 0; nt < 2; nt++) {
            int cl = wv * 32 + nt * 16 + l15;
            float bias = b1e[h * 256 + cl];
#pragma unroll
            for (int mt = 0; mt < 4; mt++)
#pragma unroll
                for (int r = 0; r < 4; r++) {
                    int row = mt * 16 + quad * 4 + r;
                    float v = hacc[mt][nt][r] + bias;
                    float g = 0.5f * v * (1.0f + erff(v * 0.70710678118654752f));
                    Hs[row * PADH + cl] = __float2bfloat16(g);
                }
        }
        __syncthreads();

        // ---- GEMM2: A = Hs rows (LDS), B = W2^T rows (global/L2), K=256
        const s16x8* b2q0 = (const s16x8*)(w2e + (size_t)(wv * 32      + l15) * HID + h * 256 + quad * 8);
        const s16x8* b2q1 = (const s16x8*)(w2e + (size_t)(wv * 32 + 16 + l15) * HID + h * 256 + quad * 8);

        s16x8 cf0 = b2q0[0], cf1 = b2q1[0];
#pragma unroll
        for (int kk = 0; kk < 8; kk++) {
            s16x8 cn0, cn1;
            if (kk < 7) { cn0 = b2q0[(kk + 1) * 4]; cn1 = b2q1[(kk + 1) * 4]; }
            s16x8 hf[4];
#pragma unroll
            for (int mt = 0; mt < 4; mt++)
                hf[mt] = *(const s16x8*)(Hs + (mt * 16 + l15) * PADH + kk * 32 + quad * 8);
#pragma unroll
            for (int mt = 0; mt < 4; mt++) {
                oacc[mt][0] = __builtin_amdgcn_mfma_f32_16x16x32_bf16(hf[mt], cf0, oacc[mt][0], 0, 0, 0);
                oacc[mt][1] = __builtin_amdgcn_mfma_f32_16x16x32_bf16(hf[mt], cf1, oacc[mt][1], 0, 0, 0);
            }
            cf0 = cn0; cf1 = cn1;
        }
        if (h == 0) __syncthreads();   // before h=1 GEMM1 epilogue overwrites Hs
    }

    // ---- epilogue: (acc + b2) * route_weight -> ybuf[slot][c] bf16
    const float* b2e = b2 + e * CCH;
#pragma unroll
    for (int nt = 0; nt < 2; nt++) {
        int cc = wv * 32 + nt * 16 + l15;
        float bias = b2e[cc];
#pragma unroll
        for (int mt = 0; mt < 4; mt++) {
#pragma unroll
            for (int r = 0; r < 4; r++) {
                int row = mt * 16 + quad * 4 + r;
                if (row < nrows) {
                    float v = (oacc[mt][nt][r] + bias) * wrow[row];
                    ybuf[(size_t)(abase + row) * CCH + cc] = __float2bfloat16(v);
                }
            }
        }
    }
}

// ---------------- K4: combine two expert outputs, transpose back, residual --
__global__ __launch_bounds__(256) void k_combine(
    const float* __restrict__ x, const __hip_bfloat16* __restrict__ ybuf,
    const int2* __restrict__ tok_slots, const float* __restrict__ scale,
    float* __restrict__ out)
{
    __shared__ float moe[CCH][65];
    __shared__ int2 slots[64];
    int tid = threadIdx.x;
    int n0 = blockIdx.x * 64;
    if (tid < 64) slots[tid] = tok_slots[n0 + tid];
    __syncthreads();
    for (int r = 0; r < 64; r++) {
        int2 s = slots[r];
        float y = __bfloat162float(ybuf[(size_t)s.x * CCH + tid]) +
                  __bfloat162float(ybuf[(size_t)s.y * CCH + tid]);
        moe[tid][r] = y;
    }
    __syncthreads();
    float sc = scale[0];
    int b = n0 >> 12, p0 = n0 & 4095;
    const float* xb = x + (size_t)b * CCH * HW + p0;
    float* ob = out + (size_t)b * CCH * HW + p0;
    int lane = tid & 63, wv = tid >> 6;
    for (int i = 0; i < 64; i++) {
        int c = i * 4 + wv;
        ob[(size_t)c * HW + lane] = xb[(size_t)c * HW + lane] + sc * moe[c][lane];
    }
}

// ---------------- launch ----------------------------------------------------
extern "C" void kernel_launch(void* const* d_in, const int* in_sizes, int n_in,
                              void* d_out, int out_size, void* d_ws, size_t ws_size,
                              hipStream_t stream)
{
    const float* x     = (const float*)d_in[0];
    const float* Wr    = (const float*)d_in[1];
    const float* br    = (const float*)d_in[2];
    const float* W1    = (const float*)d_in[3];
    const float* b1    = (const float*)d_in[4];
    const float* W2    = (const float*)d_in[5];
    const float* b2    = (const float*)d_in[6];
    const float* scale = (const float*)d_in[7];
    float* out = (float*)d_out;

    char* ws = (char*)d_ws;
    __hip_bfloat16* tokens = (__hip_bfloat16*)(ws);                 // 33,554,432 B
    __hip_bfloat16* w1t    = (__hip_bfloat16*)(ws + 33554432);      //  2,097,152 B
    __hip_bfloat16* w2t    = (__hip_bfloat16*)(ws + 35651584);      //  2,097,152 B
    __hip_bfloat16* ybuf   = (__hip_bfloat16*)(ws + 37748736);      // 67,108,864 B
    int*    assign_tok = (int*)   (ws + 104857600);                 //    524,288 B
    float*  assign_w   = (float*) (ws + 105381888);                 //    524,288 B
    int2*   tok_slots  = (int2*)  (ws + 105906176);                 //    524,288 B
    int*    pair       = (int*)   (ws + 106430464);                 //    262,144 B
    float2* wts        = (float2*)(ws + 106692608);                 //    524,288 B
    int*    meta       = (int*)   (ws + 107216896);                 //        256 B

    hipMemsetAsync(meta, 0, 64, stream);  // counts + cursors
    k_transpose_cast<<<256, 256, 0, stream>>>(W1, w1t, 256, 512);
    k_transpose_cast<<<256, 256, 0, stream>>>(W2, w2t, 512, 256);
    k_router<<<1024, 256, 0, stream>>>(x, Wr, br, tokens, pair, wts, meta);
    k_scan<<<1, 64, 0, stream>>>(meta);
    k_scatter<<<256, 256, 0, stream>>>(pair, wts, meta, assign_tok, assign_w, tok_slots);
    k_expert<<<2056, 512, 0, stream>>>(tokens, w1t, w2t, b1, b2, meta,
                                       assign_tok, assign_w, ybuf);
    k_combine<<<1024, 256, 0, stream>>>(x, ybuf, tok_slots, scale, out);
}